// Round 1
// baseline (1239.508 us; speedup 1.0000x reference)
//
#include <hip/hip_runtime.h>
#include <cstddef>

#define LQ 1024
#define DM 128
#define DI 256
#define DSN 16
#define NB 8
#define ROWS (NB*LQ)
#define EPSF 1e-5f

static __device__ __forceinline__ float sigmoid_f(float x) { return 1.f/(1.f+__expf(-x)); }

// ---------------- rmsnorm: one wave per row of 128 ----------------
__global__ __launch_bounds__(256) void rmsnorm_kernel(const float* __restrict__ x,
    const float* __restrict__ w, float* __restrict__ o) {
  int row = blockIdx.x*4 + (threadIdx.x>>6);
  int lane = threadIdx.x & 63;
  const float2 v = *(const float2*)(x + (size_t)row*DM + lane*2);
  float ss = v.x*v.x + v.y*v.y;
  #pragma unroll
  for (int m = 32; m; m >>= 1) ss += __shfl_xor(ss, m);
  float scale = rsqrtf(ss * (1.f/128.f) + EPSF);
  const float2 wv = *(const float2*)(w + lane*2);
  float2 out; out.x = v.x*scale*wv.x; out.y = v.y*scale*wv.y;
  *(float2*)(o + (size_t)row*DM + lane*2) = out;
}

// ---------------- generic fp32 GEMM: C[M,N] = A[M,K] @ W[N,K]^T (+addsrc) ----------------
#define BM 64
#define BN 64
#define BK 16
__global__ __launch_bounds__(256) void gemm_kernel(const float* __restrict__ A,
    const float* __restrict__ W, const float* __restrict__ addsrc,
    float* __restrict__ C, int M, int N, int K) {
  __shared__ float As[BK][BM];
  __shared__ float Ws[BK][BN];
  int tid = threadIdx.x;
  int row0 = blockIdx.x*BM, col0 = blockIdx.y*BN;
  int tx = tid & 15, ty = tid >> 4;
  int lr = tid >> 2;          // 0..63 tile row
  int lc = (tid & 3) * 4;     // 0,4,8,12 k-offset
  float acc[4][4] = {};
  for (int k0 = 0; k0 < K; k0 += BK) {
    float4 av = *(const float4*)(A + (size_t)(row0+lr)*K + k0 + lc);
    float4 wv = make_float4(0.f,0.f,0.f,0.f);
    int wrow = col0 + lr;
    if (wrow < N) wv = *(const float4*)(W + (size_t)wrow*K + k0 + lc);
    __syncthreads();
    As[lc+0][lr]=av.x; As[lc+1][lr]=av.y; As[lc+2][lr]=av.z; As[lc+3][lr]=av.w;
    Ws[lc+0][lr]=wv.x; Ws[lc+1][lr]=wv.y; Ws[lc+2][lr]=wv.z; Ws[lc+3][lr]=wv.w;
    __syncthreads();
    #pragma unroll
    for (int k = 0; k < BK; ++k) {
      float4 a = *(const float4*)&As[k][ty*4];
      float4 b = *(const float4*)&Ws[k][tx*4];
      acc[0][0] += a.x*b.x; acc[0][1] += a.x*b.y; acc[0][2] += a.x*b.z; acc[0][3] += a.x*b.w;
      acc[1][0] += a.y*b.x; acc[1][1] += a.y*b.y; acc[1][2] += a.y*b.z; acc[1][3] += a.y*b.w;
      acc[2][0] += a.z*b.x; acc[2][1] += a.z*b.y; acc[2][2] += a.z*b.z; acc[2][3] += a.z*b.w;
      acc[3][0] += a.w*b.x; acc[3][1] += a.w*b.y; acc[3][2] += a.w*b.z; acc[3][3] += a.w*b.w;
    }
  }
  #pragma unroll
  for (int i = 0; i < 4; ++i) {
    int r = row0 + ty*4 + i;
    #pragma unroll
    for (int j = 0; j < 4; ++j) {
      int c = col0 + tx*4 + j;
      if (c < N) {
        float v = acc[i][j];
        if (addsrc) v += addsrc[(size_t)r*N + c];
        C[(size_t)r*N + c] = v;
      }
    }
  }
}

// ---------------- causal depthwise conv (k=4) + bias + silu ----------------
__global__ __launch_bounds__(256) void conv_silu_kernel(const float* __restrict__ xz,
    const float* __restrict__ cw, const float* __restrict__ cb, float* __restrict__ xs) {
  int row = blockIdx.x;            // b*L + t
  int d = threadIdx.x;
  int t = row & (LQ-1);
  float w0=cw[d*4+0], w1=cw[d*4+1], w2=cw[d*4+2], w3=cw[d*4+3];
  float acc = cb[d];
  const float* base = xz + (size_t)row*(2*DI) + d;
  if (t >= 3) {
    acc += base[-3*(2*DI)]*w0 + base[-2*(2*DI)]*w1 + base[-(2*DI)]*w2 + base[0]*w3;
  } else {
    acc += base[0]*w3;
    if (t >= 1) acc += base[-(2*DI)]*w2;
    if (t >= 2) acc += base[-2*(2*DI)]*w1;
  }
  xs[(size_t)row*DI + d] = acc * sigmoid_f(acc);
}

// ---------------- dt_proj (K=8) + softplus ----------------
__global__ __launch_bounds__(256) void dt_kernel(const float* __restrict__ dbc,
    const float* __restrict__ dtw, const float* __restrict__ dtb, float* __restrict__ delta) {
  int row = blockIdx.x; int d = threadIdx.x;
  const float* dl = dbc + (size_t)row*40;
  float acc = dtb[d];
  #pragma unroll
  for (int j = 0; j < 8; ++j) acc += dl[j] * dtw[d*8+j];
  float sp = (acc > 20.f) ? acc : log1pf(__expf(acc));
  delta[(size_t)row*DI + d] = sp;
}

// ---------------- selective scan: block = (batch, 16-channel slab) ----------------
__global__ __launch_bounds__(256) void scan_kernel(
    const float* __restrict__ u,      // [ROWS, DI]
    const float* __restrict__ delta,  // [ROWS, DI]
    const float* __restrict__ dbc,    // [ROWS, 40]
    const float* __restrict__ A_log,  // [DI, DSN]
    const float* __restrict__ Dp,     // [DI]
    float* __restrict__ y)            // [ROWS, DI]
{
  const int b = blockIdx.x >> 4;
  const int dblk = blockIdx.x & 15;
  const int tid = threadIdx.x;
  const int wave = tid >> 6;
  const int lane = tid & 63;
  const int n = lane & 15;
  const int cl = (wave << 2) + (lane >> 4);   // 0..15 channel in slab
  const int d = dblk*16 + cl;
  const float Acoef = -__expf(A_log[d*DSN + n]);
  const float Dv = Dp[d];
  __shared__ float s_dl[64][16];
  __shared__ float s_u[64][16];
  __shared__ float s_B[64][16];
  __shared__ float s_C[64][16];
  __shared__ float s_y[64][16];
  float h = 0.f;
  for (int tile = 0; tile < LQ/64; ++tile) {
    int t0 = tile*64;
    for (int e = tid; e < 1024; e += 256) {
      int t = e >> 4, j = e & 15;
      size_t row = (size_t)(b*LQ + t0 + t);
      s_dl[t][j] = delta[row*DI + dblk*16 + j];
      s_u[t][j]  = u[row*DI + dblk*16 + j];
      s_B[t][j]  = dbc[row*40 + 8 + j];
      s_C[t][j]  = dbc[row*40 + 24 + j];
    }
    __syncthreads();
    #pragma unroll 4
    for (int t = 0; t < 64; ++t) {
      float dl = s_dl[t][cl];
      float uu = s_u[t][cl];
      float dA = __expf(dl * Acoef);
      float dBu = dl * s_B[t][n] * uu;
      h = dA*h + dBu;
      float p = h * s_C[t][n];
      p += __shfl_xor(p, 1);
      p += __shfl_xor(p, 2);
      p += __shfl_xor(p, 4);
      p += __shfl_xor(p, 8);
      if (n == 0) s_y[t][cl] = p + uu*Dv;
    }
    __syncthreads();
    for (int e = tid; e < 1024; e += 256) {
      int t = e >> 4, j = e & 15;
      y[(size_t)(b*LQ + t0 + t)*DI + dblk*16 + j] = s_y[t][j];
    }
    __syncthreads();
  }
}

// ---------------- gate: y *= silu(res) ----------------
__global__ __launch_bounds__(256) void gate_kernel(float* __restrict__ y,
    const float* __restrict__ xz) {
  int row = blockIdx.x; int d = threadIdx.x;
  float res = xz[(size_t)row*(2*DI) + DI + d];
  y[(size_t)row*DI + d] *= res * sigmoid_f(res);
}

// ---------------- final: last-token rmsnorm + batchnorm + relu + head ----------------
__global__ __launch_bounds__(256) void final_kernel(const float* __restrict__ h,
    const float* __restrict__ nfw, const float* __restrict__ gamma, const float* __restrict__ beta,
    const float* __restrict__ hw, const float* __restrict__ hb, float* __restrict__ out) {
  __shared__ float sf[8][128];
  __shared__ float sscale[8];
  int tid = threadIdx.x;
  for (int e = tid; e < 1024; e += 256) {
    int b = e >> 7, dd = e & 127;
    sf[b][dd] = h[((size_t)b*LQ + (LQ-1))*DM + dd];
  }
  __syncthreads();
  if (tid < 8) {
    float ss = 0.f;
    for (int dd = 0; dd < 128; ++dd) { float v = sf[tid][dd]; ss += v*v; }
    sscale[tid] = rsqrtf(ss/128.f + EPSF);
  }
  __syncthreads();
  for (int e = tid; e < 1024; e += 256) {
    int b = e >> 7, dd = e & 127;
    sf[b][dd] = sf[b][dd]*sscale[b]*nfw[dd];
  }
  __syncthreads();
  if (tid < 128) {
    float mu = 0.f;
    for (int b = 0; b < 8; ++b) mu += sf[b][tid];
    mu *= 0.125f;
    float var = 0.f;
    for (int b = 0; b < 8; ++b) { float dv = sf[b][tid]-mu; var += dv*dv; }
    var *= 0.125f;
    float rs = rsqrtf(var + EPSF);
    for (int b = 0; b < 8; ++b) {
      float v = (sf[b][tid]-mu)*rs*gamma[tid] + beta[tid];
      sf[b][tid] = v > 0.f ? v : 0.f;
    }
  }
  __syncthreads();
  if (tid < 16) {
    int b = tid >> 1, s = tid & 1;
    float acc = hb[s];
    for (int dd = 0; dd < 128; ++dd) acc += sf[b][dd]*hw[s*128+dd];
    out[b*2+s] = acc;
  }
}

extern "C" void kernel_launch(void* const* d_in, const int* in_sizes, int n_in,
                              void* d_out, int out_size, void* d_ws, size_t ws_size,
                              hipStream_t stream) {
  const float* x      = (const float*)d_in[0];
  const float* in_w   = (const float*)d_in[1];
  const float* conv_w = (const float*)d_in[2];
  const float* conv_b = (const float*)d_in[3];
  const float* xp_w   = (const float*)d_in[4];
  const float* dt_w   = (const float*)d_in[5];
  const float* dt_b   = (const float*)d_in[6];
  const float* A_log  = (const float*)d_in[7];
  const float* Dp     = (const float*)d_in[8];
  const float* out_w  = (const float*)d_in[9];
  const float* norm_w = (const float*)d_in[10];
  const float* norm_f = (const float*)d_in[11];
  const float* gamma  = (const float*)d_in[12];
  const float* beta   = (const float*)d_in[13];
  const float* head_w = (const float*)d_in[14];
  const float* head_b = (const float*)d_in[15];

  float* ws = (float*)d_ws;
  float* h     = ws;                         // ROWS*DM       = 1,048,576
  float* xz    = h + (size_t)ROWS*DM;        // ROWS*512      = 4,194,304
  float* xs    = xz + (size_t)ROWS*2*DI;     // ROWS*256      = 2,097,152
  float* dbc   = xs + (size_t)ROWS*DI;       // ROWS*40       =   327,680
  float* delta = dbc + (size_t)ROWS*40;      // ROWS*256      = 2,097,152
  float* y     = delta + (size_t)ROWS*DI;    // ROWS*256      = 2,097,152
  float* xn    = y;                          // alias: xn consumed before scan writes y

  hipMemcpyAsync(h, x, (size_t)ROWS*DM*sizeof(float), hipMemcpyDeviceToDevice, stream);

  for (int layer = 0; layer < 4; ++layer) {
    const float* lw_in  = in_w  + (size_t)layer*2*DI*DM;
    const float* lw_cw  = conv_w + (size_t)layer*DI*4;
    const float* lw_cb  = conv_b + (size_t)layer*DI;
    const float* lw_xp  = xp_w  + (size_t)layer*40*DI;
    const float* lw_dtw = dt_w  + (size_t)layer*DI*8;
    const float* lw_dtb = dt_b  + (size_t)layer*DI;
    const float* lw_Al  = A_log + (size_t)layer*DI*DSN;
    const float* lw_D   = Dp    + (size_t)layer*DI;
    const float* lw_out = out_w + (size_t)layer*DM*DI;
    const float* lw_nw  = norm_w + (size_t)layer*DM;

    rmsnorm_kernel<<<ROWS/4, 256, 0, stream>>>(h, lw_nw, xn);
    gemm_kernel<<<dim3(ROWS/BM, (2*DI)/BN), 256, 0, stream>>>(xn, lw_in, nullptr, xz, ROWS, 2*DI, DM);
    conv_silu_kernel<<<ROWS, 256, 0, stream>>>(xz, lw_cw, lw_cb, xs);
    gemm_kernel<<<dim3(ROWS/BM, 1), 256, 0, stream>>>(xs, lw_xp, nullptr, dbc, ROWS, 40, DI);
    dt_kernel<<<ROWS, 256, 0, stream>>>(dbc, lw_dtw, lw_dtb, delta);
    scan_kernel<<<NB*16, 256, 0, stream>>>(xs, delta, dbc, lw_Al, lw_D, y);
    gate_kernel<<<ROWS, 256, 0, stream>>>(y, xz);
    gemm_kernel<<<dim3(ROWS/BM, DM/BN), 256, 0, stream>>>(y, lw_out, h, h, ROWS, DM, DI);
  }
  final_kernel<<<1, 256, 0, stream>>>(h, norm_f, gamma, beta, head_w, head_b, (float*)d_out);
}

// Round 2
// 497.502 us; speedup vs baseline: 2.4915x; 2.4915x over previous
//
#include <hip/hip_runtime.h>
#include <cstddef>

#define LQ 1024
#define DM 128
#define DI 256
#define DSN 16
#define NB 8
#define ROWS (NB*LQ)
#define EPSF 1e-5f
#define CHUNK 32
#define NCHUNK (LQ/CHUNK)

static __device__ __forceinline__ float sigmoid_f(float x) { return 1.f/(1.f+__expf(-x)); }

// ---------------- rmsnorm: one wave per row of 128 ----------------
__global__ __launch_bounds__(256) void rmsnorm_kernel(const float* __restrict__ x,
    const float* __restrict__ w, float* __restrict__ o) {
  int row = blockIdx.x*4 + (threadIdx.x>>6);
  int lane = threadIdx.x & 63;
  const float2 v = *(const float2*)(x + (size_t)row*DM + lane*2);
  float ss = v.x*v.x + v.y*v.y;
  #pragma unroll
  for (int m = 32; m; m >>= 1) ss += __shfl_xor(ss, m);
  float scale = rsqrtf(ss * (1.f/128.f) + EPSF);
  const float2 wv = *(const float2*)(w + lane*2);
  float2 out; out.x = v.x*scale*wv.x; out.y = v.y*scale*wv.y;
  *(float2*)(o + (size_t)row*DM + lane*2) = out;
}

// ---------------- generic fp32 GEMM: C[M,N] = A[M,K] @ W[N,K]^T (+addsrc) ----------------
#define BM 64
#define BN 64
#define BK 16
__global__ __launch_bounds__(256) void gemm_kernel(const float* __restrict__ A,
    const float* __restrict__ W, const float* __restrict__ addsrc,
    float* __restrict__ C, int M, int N, int K) {
  __shared__ float As[BK][BM];
  __shared__ float Ws[BK][BN];
  int tid = threadIdx.x;
  int row0 = blockIdx.x*BM, col0 = blockIdx.y*BN;
  int tx = tid & 15, ty = tid >> 4;
  int lr = tid >> 2;          // 0..63 tile row
  int lc = (tid & 3) * 4;     // 0,4,8,12 k-offset
  float acc[4][4] = {};
  for (int k0 = 0; k0 < K; k0 += BK) {
    float4 av = *(const float4*)(A + (size_t)(row0+lr)*K + k0 + lc);
    float4 wv = make_float4(0.f,0.f,0.f,0.f);
    int wrow = col0 + lr;
    if (wrow < N) wv = *(const float4*)(W + (size_t)wrow*K + k0 + lc);
    __syncthreads();
    As[lc+0][lr]=av.x; As[lc+1][lr]=av.y; As[lc+2][lr]=av.z; As[lc+3][lr]=av.w;
    Ws[lc+0][lr]=wv.x; Ws[lc+1][lr]=wv.y; Ws[lc+2][lr]=wv.z; Ws[lc+3][lr]=wv.w;
    __syncthreads();
    #pragma unroll
    for (int k = 0; k < BK; ++k) {
      float4 a = *(const float4*)&As[k][ty*4];
      float4 b = *(const float4*)&Ws[k][tx*4];
      acc[0][0] += a.x*b.x; acc[0][1] += a.x*b.y; acc[0][2] += a.x*b.z; acc[0][3] += a.x*b.w;
      acc[1][0] += a.y*b.x; acc[1][1] += a.y*b.y; acc[1][2] += a.y*b.z; acc[1][3] += a.y*b.w;
      acc[2][0] += a.z*b.x; acc[2][1] += a.z*b.y; acc[2][2] += a.z*b.z; acc[2][3] += a.z*b.w;
      acc[3][0] += a.w*b.x; acc[3][1] += a.w*b.y; acc[3][2] += a.w*b.z; acc[3][3] += a.w*b.w;
    }
  }
  #pragma unroll
  for (int i = 0; i < 4; ++i) {
    int r = row0 + ty*4 + i;
    #pragma unroll
    for (int j = 0; j < 4; ++j) {
      int c = col0 + tx*4 + j;
      if (c < N) {
        float v = acc[i][j];
        if (addsrc) v += addsrc[(size_t)r*N + c];
        C[(size_t)r*N + c] = v;
      }
    }
  }
}

// ---------------- causal depthwise conv (k=4) + bias + silu ----------------
__global__ __launch_bounds__(256) void conv_silu_kernel(const float* __restrict__ xz,
    const float* __restrict__ cw, const float* __restrict__ cb, float* __restrict__ xs) {
  int row = blockIdx.x;            // b*L + t
  int d = threadIdx.x;
  int t = row & (LQ-1);
  float w0=cw[d*4+0], w1=cw[d*4+1], w2=cw[d*4+2], w3=cw[d*4+3];
  float acc = cb[d];
  const float* base = xz + (size_t)row*(2*DI) + d;
  if (t >= 3) {
    acc += base[-3*(2*DI)]*w0 + base[-2*(2*DI)]*w1 + base[-(2*DI)]*w2 + base[0]*w3;
  } else {
    acc += base[0]*w3;
    if (t >= 1) acc += base[-(2*DI)]*w2;
    if (t >= 2) acc += base[-2*(2*DI)]*w1;
  }
  xs[(size_t)row*DI + d] = acc * sigmoid_f(acc);
}

// ---------------- dt_proj (K=8) + softplus ----------------
__global__ __launch_bounds__(256) void dt_kernel(const float* __restrict__ dbc,
    const float* __restrict__ dtw, const float* __restrict__ dtb, float* __restrict__ delta) {
  int row = blockIdx.x; int d = threadIdx.x;
  const float* dl = dbc + (size_t)row*40;
  float acc = dtb[d];
  #pragma unroll
  for (int j = 0; j < 8; ++j) acc += dl[j] * dtw[d*8+j];
  float sp = (acc > 20.f) ? acc : log1pf(__expf(acc));
  delta[(size_t)row*DI + d] = sp;
}

// ---------------- scan phase 1: per-chunk local scan -> S (local final state), sum(delta) ----------------
__global__ __launch_bounds__(256) void scan_p1(
    const float* __restrict__ u, const float* __restrict__ delta,
    const float* __restrict__ dbc, const float* __restrict__ A_log,
    float* __restrict__ S, float* __restrict__ sumdl_out)
{
  const int bc = blockIdx.x;            // b*NCHUNK + c
  const int b = bc >> 5, c = bc & (NCHUNK-1);
  const int d = threadIdx.x;
  __shared__ float sB[CHUNK][16];
  for (int e = threadIdx.x; e < CHUNK*16; e += 256) {
    int t = e >> 4, n = e & 15;
    sB[t][n] = dbc[(size_t)(b*LQ + c*CHUNK + t)*40 + 8 + n];
  }
  float A[16];
  #pragma unroll
  for (int n = 0; n < 16; ++n) A[n] = -__expf(A_log[d*16+n]);
  __syncthreads();
  float h[16] = {};
  float sdl = 0.f;
  size_t base = (size_t)(b*LQ + c*CHUNK)*DI + d;
  for (int t = 0; t < CHUNK; ++t) {
    float dl = delta[base + (size_t)t*DI];
    float uu = u[base + (size_t)t*DI];
    float du = dl*uu;
    sdl += dl;
    #pragma unroll
    for (int n = 0; n < 16; ++n)
      h[n] = __expf(dl*A[n])*h[n] + du*sB[t][n];
  }
  float* Sp = S + ((size_t)bc*DI + d)*16;
  #pragma unroll
  for (int n = 0; n < 16; n += 4)
    *(float4*)(Sp+n) = make_float4(h[n],h[n+1],h[n+2],h[n+3]);
  sumdl_out[(size_t)bc*DI + d] = sdl;
}

// ---------------- scan phase 2: exclusive scan over chunks (in-place S -> Hinit) ----------------
__global__ __launch_bounds__(256) void scan_p2(
    float* __restrict__ S, const float* __restrict__ sumdl,
    const float* __restrict__ A_log)
{
  int g = blockIdx.x*256 + threadIdx.x;   // b*4096 + d*16 + n
  int b = g >> 12;
  int dn = g & 4095;
  float A = -__expf(A_log[dn]);
  int d = dn >> 4;
  float H = 0.f;
  for (int c = 0; c < NCHUNK; ++c) {
    size_t cidx = (size_t)(b*NCHUNK + c)*DI + d;
    size_t idx = ((size_t)(b*NCHUNK + c)*DI + d)*16 + (dn & 15);
    float Sv = S[idx];
    float P = __expf(A * sumdl[cidx]);
    S[idx] = H;
    H = P*H + Sv;
  }
}

// ---------------- scan phase 3: seeded local scan -> y, fused with silu(res) gate ----------------
__global__ __launch_bounds__(256) void scan_p3(
    const float* __restrict__ u, const float* __restrict__ delta,
    const float* __restrict__ dbc, const float* __restrict__ A_log,
    const float* __restrict__ Dp, const float* __restrict__ Hinit,
    const float* __restrict__ xz, float* __restrict__ y)
{
  const int bc = blockIdx.x;
  const int b = bc >> 5, c = bc & (NCHUNK-1);
  const int d = threadIdx.x;
  __shared__ float sB[CHUNK][16];
  __shared__ float sC[CHUNK][16];
  for (int e = threadIdx.x; e < CHUNK*16; e += 256) {
    int t = e >> 4, n = e & 15;
    size_t r = (size_t)(b*LQ + c*CHUNK + t)*40;
    sB[t][n] = dbc[r + 8 + n];
    sC[t][n] = dbc[r + 24 + n];
  }
  float A[16];
  #pragma unroll
  for (int n = 0; n < 16; ++n) A[n] = -__expf(A_log[d*16+n]);
  float h[16];
  const float* Hp = Hinit + ((size_t)bc*DI + d)*16;
  #pragma unroll
  for (int n = 0; n < 16; n += 4) {
    float4 v = *(const float4*)(Hp+n);
    h[n]=v.x; h[n+1]=v.y; h[n+2]=v.z; h[n+3]=v.w;
  }
  const float Dv = Dp[d];
  __syncthreads();
  size_t base = (size_t)(b*LQ + c*CHUNK)*DI + d;
  size_t xzbase = (size_t)(b*LQ + c*CHUNK)*(2*DI) + DI + d;
  for (int t = 0; t < CHUNK; ++t) {
    float dl = delta[base + (size_t)t*DI];
    float uu = u[base + (size_t)t*DI];
    float du = dl*uu;
    float acc = uu*Dv;
    #pragma unroll
    for (int n = 0; n < 16; ++n) {
      h[n] = __expf(dl*A[n])*h[n] + du*sB[t][n];
      acc += h[n]*sC[t][n];
    }
    float res = xz[xzbase + (size_t)t*(2*DI)];
    y[base + (size_t)t*DI] = acc * (res * sigmoid_f(res));
  }
}

// ---------------- final: last-token rmsnorm + batchnorm + relu + head ----------------
__global__ __launch_bounds__(256) void final_kernel(const float* __restrict__ h,
    const float* __restrict__ nfw, const float* __restrict__ gamma, const float* __restrict__ beta,
    const float* __restrict__ hw, const float* __restrict__ hb, float* __restrict__ out) {
  __shared__ float sf[8][128];
  __shared__ float sscale[8];
  int tid = threadIdx.x;
  for (int e = tid; e < 1024; e += 256) {
    int b = e >> 7, dd = e & 127;
    sf[b][dd] = h[((size_t)b*LQ + (LQ-1))*DM + dd];
  }
  __syncthreads();
  if (tid < 8) {
    float ss = 0.f;
    for (int dd = 0; dd < 128; ++dd) { float v = sf[tid][dd]; ss += v*v; }
    sscale[tid] = rsqrtf(ss/128.f + EPSF);
  }
  __syncthreads();
  for (int e = tid; e < 1024; e += 256) {
    int b = e >> 7, dd = e & 127;
    sf[b][dd] = sf[b][dd]*sscale[b]*nfw[dd];
  }
  __syncthreads();
  if (tid < 128) {
    float mu = 0.f;
    for (int b = 0; b < 8; ++b) mu += sf[b][tid];
    mu *= 0.125f;
    float var = 0.f;
    for (int b = 0; b < 8; ++b) { float dv = sf[b][tid]-mu; var += dv*dv; }
    var *= 0.125f;
    float rs = rsqrtf(var + EPSF);
    for (int b = 0; b < 8; ++b) {
      float v = (sf[b][tid]-mu)*rs*gamma[tid] + beta[tid];
      sf[b][tid] = v > 0.f ? v : 0.f;
    }
  }
  __syncthreads();
  if (tid < 16) {
    int b = tid >> 1, s = tid & 1;
    float acc = hb[s];
    for (int dd = 0; dd < 128; ++dd) acc += sf[b][dd]*hw[s*128+dd];
    out[b*2+s] = acc;
  }
}

extern "C" void kernel_launch(void* const* d_in, const int* in_sizes, int n_in,
                              void* d_out, int out_size, void* d_ws, size_t ws_size,
                              hipStream_t stream) {
  const float* x      = (const float*)d_in[0];
  const float* in_w   = (const float*)d_in[1];
  const float* conv_w = (const float*)d_in[2];
  const float* conv_b = (const float*)d_in[3];
  const float* xp_w   = (const float*)d_in[4];
  const float* dt_w   = (const float*)d_in[5];
  const float* dt_b   = (const float*)d_in[6];
  const float* A_log  = (const float*)d_in[7];
  const float* Dp     = (const float*)d_in[8];
  const float* out_w  = (const float*)d_in[9];
  const float* norm_w = (const float*)d_in[10];
  const float* norm_f = (const float*)d_in[11];
  const float* gamma  = (const float*)d_in[12];
  const float* beta   = (const float*)d_in[13];
  const float* head_w = (const float*)d_in[14];
  const float* head_b = (const float*)d_in[15];

  float* ws = (float*)d_ws;
  float* h     = ws;                         // ROWS*DM
  float* xz    = h + (size_t)ROWS*DM;        // ROWS*512
  float* xs    = xz + (size_t)ROWS*2*DI;     // ROWS*256
  float* dbc   = xs + (size_t)ROWS*DI;       // ROWS*40
  float* delta = dbc + (size_t)ROWS*40;      // ROWS*256
  float* y     = delta + (size_t)ROWS*DI;    // ROWS*256
  float* S     = y + (size_t)ROWS*DI;        // B*NCHUNK*DI*16 = 1,048,576
  float* sumdl = S + (size_t)NB*NCHUNK*DI*16; // B*NCHUNK*DI   = 65,536
  float* xn    = y;                          // alias: xn consumed before scan writes y

  hipMemcpyAsync(h, x, (size_t)ROWS*DM*sizeof(float), hipMemcpyDeviceToDevice, stream);

  for (int layer = 0; layer < 4; ++layer) {
    const float* lw_in  = in_w  + (size_t)layer*2*DI*DM;
    const float* lw_cw  = conv_w + (size_t)layer*DI*4;
    const float* lw_cb  = conv_b + (size_t)layer*DI;
    const float* lw_xp  = xp_w  + (size_t)layer*40*DI;
    const float* lw_dtw = dt_w  + (size_t)layer*DI*8;
    const float* lw_dtb = dt_b  + (size_t)layer*DI;
    const float* lw_Al  = A_log + (size_t)layer*DI*DSN;
    const float* lw_D   = Dp    + (size_t)layer*DI;
    const float* lw_out = out_w + (size_t)layer*DM*DI;
    const float* lw_nw  = norm_w + (size_t)layer*DM;

    rmsnorm_kernel<<<ROWS/4, 256, 0, stream>>>(h, lw_nw, xn);
    gemm_kernel<<<dim3(ROWS/BM, (2*DI)/BN), 256, 0, stream>>>(xn, lw_in, nullptr, xz, ROWS, 2*DI, DM);
    conv_silu_kernel<<<ROWS, 256, 0, stream>>>(xz, lw_cw, lw_cb, xs);
    gemm_kernel<<<dim3(ROWS/BM, 1), 256, 0, stream>>>(xs, lw_xp, nullptr, dbc, ROWS, 40, DI);
    dt_kernel<<<ROWS, 256, 0, stream>>>(dbc, lw_dtw, lw_dtb, delta);
    scan_p1<<<NB*NCHUNK, 256, 0, stream>>>(xs, delta, dbc, lw_Al, S, sumdl);
    scan_p2<<<NB*DI*DSN/256, 256, 0, stream>>>(S, sumdl, lw_Al);
    scan_p3<<<NB*NCHUNK, 256, 0, stream>>>(xs, delta, dbc, lw_Al, lw_D, S, xz, y);
    gemm_kernel<<<dim3(ROWS/BM, DM/BN), 256, 0, stream>>>(y, lw_out, h, h, ROWS, DM, DI);
  }
  final_kernel<<<1, 256, 0, stream>>>(h, norm_f, gamma, beta, head_w, head_b, (float*)d_out);
}

// Round 3
// 380.584 us; speedup vs baseline: 3.2569x; 1.3072x over previous
//
#include <hip/hip_runtime.h>
#include <cstddef>

#define LQ 1024
#define DM 128
#define DI 256
#define DSN 16
#define NB 8
#define ROWS (NB*LQ)
#define EPSF 1e-5f
#define CHUNK 32
#define NCHUNK (LQ/CHUNK)

typedef _Float16 f16;
typedef __attribute__((ext_vector_type(8))) _Float16 f16x8;
typedef __attribute__((ext_vector_type(4))) _Float16 f16x4;
typedef __attribute__((ext_vector_type(2))) _Float16 f16x2;
typedef __attribute__((ext_vector_type(4))) float f32x4;

static __device__ __forceinline__ float sigmoid_f(float x) { return 1.f/(1.f+__expf(-x)); }
static __device__ __forceinline__ float softplus_f(float x) {
  return (x > 20.f) ? x : log1pf(__expf(x));
}

// ---------------- weight fp32 -> fp16 (once) ----------------
__global__ __launch_bounds__(256) void cvt_kernel(const float* __restrict__ in,
    f16* __restrict__ out, int n4) {
  int i = blockIdx.x*256 + threadIdx.x;
  if (i >= n4) return;
  float4 v = ((const float4*)in)[i];
  f16x4 o; o.x=(f16)v.x; o.y=(f16)v.y; o.z=(f16)v.z; o.w=(f16)v.w;
  ((f16x4*)out)[i] = o;
}

// ---------------- rmsnorm: one wave per row of 128, fp16 out ----------------
__global__ __launch_bounds__(256) void rmsnorm_kernel(const float* __restrict__ x,
    const float* __restrict__ w, f16* __restrict__ o) {
  int row = blockIdx.x*4 + (threadIdx.x>>6);
  int lane = threadIdx.x & 63;
  const float2 v = *(const float2*)(x + (size_t)row*DM + lane*2);
  float ss = v.x*v.x + v.y*v.y;
  #pragma unroll
  for (int m = 32; m; m >>= 1) ss += __shfl_xor(ss, m);
  float scale = rsqrtf(ss * (1.f/128.f) + EPSF);
  const float2 wv = *(const float2*)(w + lane*2);
  f16x2 out; out.x = (f16)(v.x*scale*wv.x); out.y = (f16)(v.y*scale*wv.y);
  *(f16x2*)(o + (size_t)row*DM + lane*2) = out;
}

// ---------------- f16 MFMA GEMM: C[M,N] = A[M,K] @ W[N,K]^T ----------------
// BM=64, BN=64, BK=64, 256 threads = 4 waves, each wave 32x32 (2x2 frags of 16x16)
template<bool OUT16, bool ADD>
__global__ __launch_bounds__(256) void gemm_f16(const f16* __restrict__ A,
    const f16* __restrict__ W, const float* __restrict__ addsrc,
    void* __restrict__ C, int M, int N, int K) {
  __shared__ f16 Alds[64][72];
  __shared__ f16 Blds[64][72];
  const int tid = threadIdx.x;
  const int row0 = blockIdx.x*64, col0 = blockIdx.y*64;
  const int l = tid & 63;
  const int w = tid >> 6;
  const int wr = w >> 1, wc = w & 1;
  const int fr = l & 15;      // frag row/col
  const int kg = l >> 4;      // k-subgroup 0..3
  f32x4 acc[2][2];
  #pragma unroll
  for (int m = 0; m < 2; ++m)
    #pragma unroll
    for (int n = 0; n < 2; ++n)
      acc[m][n] = (f32x4){0.f,0.f,0.f,0.f};

  for (int k0 = 0; k0 < K; k0 += 64) {
    __syncthreads();
    #pragma unroll
    for (int c = tid; c < 512; c += 256) {
      int r = c >> 3, ks = (c & 7) << 3;
      *(f16x8*)&Alds[r][ks] = *(const f16x8*)(A + (size_t)(row0+r)*K + k0 + ks);
      int wrow = col0 + r;
      f16x8 bv = (f16x8){0,0,0,0,0,0,0,0};
      if (wrow < N) bv = *(const f16x8*)(W + (size_t)wrow*K + k0 + ks);
      *(f16x8*)&Blds[r][ks] = bv;
    }
    __syncthreads();
    f16x8 af[2][2], bf[2][2];
    #pragma unroll
    for (int m = 0; m < 2; ++m)
      #pragma unroll
      for (int s = 0; s < 2; ++s)
        af[m][s] = *(const f16x8*)&Alds[wr*32 + m*16 + fr][s*32 + kg*8];
    #pragma unroll
    for (int n = 0; n < 2; ++n)
      #pragma unroll
      for (int s = 0; s < 2; ++s)
        bf[n][s] = *(const f16x8*)&Blds[wc*32 + n*16 + fr][s*32 + kg*8];
    #pragma unroll
    for (int m = 0; m < 2; ++m)
      #pragma unroll
      for (int n = 0; n < 2; ++n)
        #pragma unroll
        for (int s = 0; s < 2; ++s)
          acc[m][n] = __builtin_amdgcn_mfma_f32_16x16x32_f16(af[m][s], bf[n][s], acc[m][n], 0, 0, 0);
  }
  // C/D layout: col = lane&15, row = (lane>>4)*4 + reg
  #pragma unroll
  for (int m = 0; m < 2; ++m) {
    #pragma unroll
    for (int n = 0; n < 2; ++n) {
      int c = col0 + wc*32 + n*16 + fr;
      if (c < N) {
        #pragma unroll
        for (int j = 0; j < 4; ++j) {
          int r = row0 + wr*32 + m*16 + kg*4 + j;
          float v = acc[m][n][j];
          if (ADD) v += addsrc[(size_t)r*N + c];
          if (OUT16) ((f16*)C)[(size_t)r*N + c] = (f16)v;
          else       ((float*)C)[(size_t)r*N + c] = v;
        }
      }
    }
  }
}

// ---------------- causal depthwise conv (k=4) + bias + silu, fp16 in/out ----------------
__global__ __launch_bounds__(256) void conv_silu_kernel(const f16* __restrict__ xz,
    const float* __restrict__ cw, const float* __restrict__ cb, f16* __restrict__ xs) {
  int row = blockIdx.x;            // b*L + t
  int d = threadIdx.x;
  int t = row & (LQ-1);
  float w0=cw[d*4+0], w1=cw[d*4+1], w2=cw[d*4+2], w3=cw[d*4+3];
  float acc = cb[d];
  const f16* base = xz + (size_t)row*(2*DI) + d;
  if (t >= 3) {
    acc += (float)base[-3*(2*DI)]*w0 + (float)base[-2*(2*DI)]*w1 + (float)base[-(2*DI)]*w2 + (float)base[0]*w3;
  } else {
    acc += (float)base[0]*w3;
    if (t >= 1) acc += (float)base[-(2*DI)]*w2;
    if (t >= 2) acc += (float)base[-2*(2*DI)]*w1;
  }
  xs[(size_t)row*DI + d] = (f16)(acc * sigmoid_f(acc));
}

// ---------------- scan phase 1: per-chunk local scan (dt fused) -> S, sum(delta) ----------------
__global__ __launch_bounds__(256) void scan_p1(
    const f16* __restrict__ u, const float* __restrict__ dbc,
    const float* __restrict__ A_log, const float* __restrict__ dtw,
    const float* __restrict__ dtb,
    float* __restrict__ S, float* __restrict__ sumdl_out)
{
  const int bc = blockIdx.x;            // b*NCHUNK + c
  const int b = bc >> 5, c = bc & (NCHUNK-1);
  const int d = threadIdx.x;
  __shared__ float sB[CHUNK][16];
  __shared__ float sDL[CHUNK][8];
  for (int e = threadIdx.x; e < CHUNK*16; e += 256) {
    int t = e >> 4, n = e & 15;
    sB[t][n] = dbc[(size_t)(b*LQ + c*CHUNK + t)*40 + 8 + n];
  }
  for (int e = threadIdx.x; e < CHUNK*8; e += 256) {
    int t = e >> 3, j = e & 7;
    sDL[t][j] = dbc[(size_t)(b*LQ + c*CHUNK + t)*40 + j];
  }
  float A[16];
  #pragma unroll
  for (int n = 0; n < 16; ++n) A[n] = -__expf(A_log[d*16+n]);
  const float4 dw0 = *(const float4*)(dtw + d*8);
  const float4 dw1 = *(const float4*)(dtw + d*8 + 4);
  const float bt = dtb[d];
  __syncthreads();
  float h[16] = {};
  float sdl = 0.f;
  size_t base = (size_t)(b*LQ + c*CHUNK)*DI + d;
  for (int t = 0; t < CHUNK; ++t) {
    float xa = bt + sDL[t][0]*dw0.x + sDL[t][1]*dw0.y + sDL[t][2]*dw0.z + sDL[t][3]*dw0.w
                  + sDL[t][4]*dw1.x + sDL[t][5]*dw1.y + sDL[t][6]*dw1.z + sDL[t][7]*dw1.w;
    float dl = softplus_f(xa);
    float uu = (float)u[base + (size_t)t*DI];
    float du = dl*uu;
    sdl += dl;
    #pragma unroll
    for (int n = 0; n < 16; ++n)
      h[n] = __expf(dl*A[n])*h[n] + du*sB[t][n];
  }
  float* Sp = S + ((size_t)bc*DI + d)*16;
  #pragma unroll
  for (int n = 0; n < 16; n += 4)
    *(float4*)(Sp+n) = make_float4(h[n],h[n+1],h[n+2],h[n+3]);
  sumdl_out[(size_t)bc*DI + d] = sdl;
}

// ---------------- scan phase 2: exclusive scan over chunks (in-place S -> Hinit) ----------------
__global__ __launch_bounds__(256) void scan_p2(
    float* __restrict__ S, const float* __restrict__ sumdl,
    const float* __restrict__ A_log)
{
  int g = blockIdx.x*256 + threadIdx.x;   // b*4096 + d*16 + n
  int b = g >> 12;
  int dn = g & 4095;
  float A = -__expf(A_log[dn]);
  int d = dn >> 4;
  float H = 0.f;
  for (int c = 0; c < NCHUNK; ++c) {
    size_t cidx = (size_t)(b*NCHUNK + c)*DI + d;
    size_t idx = cidx*16 + (dn & 15);
    float Sv = S[idx];
    float P = __expf(A * sumdl[cidx]);
    S[idx] = H;
    H = P*H + Sv;
  }
}

// ---------------- scan phase 3: seeded local scan (dt fused) -> y = scan*gate, fp16 ----------------
__global__ __launch_bounds__(256) void scan_p3(
    const f16* __restrict__ u, const float* __restrict__ dbc,
    const float* __restrict__ A_log, const float* __restrict__ dtw,
    const float* __restrict__ dtb, const float* __restrict__ Dp,
    const float* __restrict__ Hinit, const f16* __restrict__ xz,
    f16* __restrict__ y)
{
  const int bc = blockIdx.x;
  const int b = bc >> 5, c = bc & (NCHUNK-1);
  const int d = threadIdx.x;
  __shared__ float sB[CHUNK][16];
  __shared__ float sC[CHUNK][16];
  __shared__ float sDL[CHUNK][8];
  for (int e = threadIdx.x; e < CHUNK*16; e += 256) {
    int t = e >> 4, n = e & 15;
    size_t r = (size_t)(b*LQ + c*CHUNK + t)*40;
    sB[t][n] = dbc[r + 8 + n];
    sC[t][n] = dbc[r + 24 + n];
  }
  for (int e = threadIdx.x; e < CHUNK*8; e += 256) {
    int t = e >> 3, j = e & 7;
    sDL[t][j] = dbc[(size_t)(b*LQ + c*CHUNK + t)*40 + j];
  }
  float A[16];
  #pragma unroll
  for (int n = 0; n < 16; ++n) A[n] = -__expf(A_log[d*16+n]);
  const float4 dw0 = *(const float4*)(dtw + d*8);
  const float4 dw1 = *(const float4*)(dtw + d*8 + 4);
  const float bt = dtb[d];
  float h[16];
  const float* Hp = Hinit + ((size_t)bc*DI + d)*16;
  #pragma unroll
  for (int n = 0; n < 16; n += 4) {
    float4 v = *(const float4*)(Hp+n);
    h[n]=v.x; h[n+1]=v.y; h[n+2]=v.z; h[n+3]=v.w;
  }
  const float Dv = Dp[d];
  __syncthreads();
  size_t base = (size_t)(b*LQ + c*CHUNK)*DI + d;
  size_t xzbase = (size_t)(b*LQ + c*CHUNK)*(2*DI) + DI + d;
  for (int t = 0; t < CHUNK; ++t) {
    float xa = bt + sDL[t][0]*dw0.x + sDL[t][1]*dw0.y + sDL[t][2]*dw0.z + sDL[t][3]*dw0.w
                  + sDL[t][4]*dw1.x + sDL[t][5]*dw1.y + sDL[t][6]*dw1.z + sDL[t][7]*dw1.w;
    float dl = softplus_f(xa);
    float uu = (float)u[base + (size_t)t*DI];
    float du = dl*uu;
    float acc = uu*Dv;
    #pragma unroll
    for (int n = 0; n < 16; ++n) {
      h[n] = __expf(dl*A[n])*h[n] + du*sB[t][n];
      acc += h[n]*sC[t][n];
    }
    float res = (float)xz[xzbase + (size_t)t*(2*DI)];
    y[base + (size_t)t*DI] = (f16)(acc * (res * sigmoid_f(res)));
  }
}

// ---------------- final: last-token rmsnorm + batchnorm + relu + head ----------------
__global__ __launch_bounds__(256) void final_kernel(const float* __restrict__ h,
    const float* __restrict__ nfw, const float* __restrict__ gamma, const float* __restrict__ beta,
    const float* __restrict__ hw, const float* __restrict__ hb, float* __restrict__ out) {
  __shared__ float sf[8][128];
  __shared__ float sscale[8];
  int tid = threadIdx.x;
  for (int e = tid; e < 1024; e += 256) {
    int b = e >> 7, dd = e & 127;
    sf[b][dd] = h[((size_t)b*LQ + (LQ-1))*DM + dd];
  }
  __syncthreads();
  if (tid < 8) {
    float ss = 0.f;
    for (int dd = 0; dd < 128; ++dd) { float v = sf[tid][dd]; ss += v*v; }
    sscale[tid] = rsqrtf(ss/128.f + EPSF);
  }
  __syncthreads();
  for (int e = tid; e < 1024; e += 256) {
    int b = e >> 7, dd = e & 127;
    sf[b][dd] = sf[b][dd]*sscale[b]*nfw[dd];
  }
  __syncthreads();
  if (tid < 128) {
    float mu = 0.f;
    for (int b = 0; b < 8; ++b) mu += sf[b][tid];
    mu *= 0.125f;
    float var = 0.f;
    for (int b = 0; b < 8; ++b) { float dv = sf[b][tid]-mu; var += dv*dv; }
    var *= 0.125f;
    float rs = rsqrtf(var + EPSF);
    for (int b = 0; b < 8; ++b) {
      float v = (sf[b][tid]-mu)*rs*gamma[tid] + beta[tid];
      sf[b][tid] = v > 0.f ? v : 0.f;
    }
  }
  __syncthreads();
  if (tid < 16) {
    int b = tid >> 1, s = tid & 1;
    float acc = hb[s];
    for (int dd = 0; dd < 128; ++dd) acc += sf[b][dd]*hw[s*128+dd];
    out[b*2+s] = acc;
  }
}

extern "C" void kernel_launch(void* const* d_in, const int* in_sizes, int n_in,
                              void* d_out, int out_size, void* d_ws, size_t ws_size,
                              hipStream_t stream) {
  const float* x      = (const float*)d_in[0];
  const float* in_w   = (const float*)d_in[1];
  const float* conv_w = (const float*)d_in[2];
  const float* conv_b = (const float*)d_in[3];
  const float* xp_w   = (const float*)d_in[4];
  const float* dt_w   = (const float*)d_in[5];
  const float* dt_b   = (const float*)d_in[6];
  const float* A_log  = (const float*)d_in[7];
  const float* Dp     = (const float*)d_in[8];
  const float* out_w  = (const float*)d_in[9];
  const float* norm_w = (const float*)d_in[10];
  const float* norm_f = (const float*)d_in[11];
  const float* gamma  = (const float*)d_in[12];
  const float* beta   = (const float*)d_in[13];
  const float* head_w = (const float*)d_in[14];
  const float* head_b = (const float*)d_in[15];

  float* ws = (float*)d_ws;
  float* h     = ws;                           // ROWS*DM fp32
  float* dbc   = h + (size_t)ROWS*DM;          // ROWS*40 fp32
  float* S     = dbc + (size_t)ROWS*40;        // NB*NCHUNK*DI*16 fp32
  float* sumdl = S + (size_t)NB*NCHUNK*DI*16;  // NB*NCHUNK*DI fp32
  f16* xz   = (f16*)(sumdl + (size_t)NB*NCHUNK*DI);   // ROWS*512 f16
  f16* xs   = xz + (size_t)ROWS*2*DI;                 // ROWS*256 f16
  f16* xn   = xs + (size_t)ROWS*DI;                   // ROWS*128 f16
  f16* y    = xn + (size_t)ROWS*DM;                   // ROWS*256 f16
  f16* wf_in  = y + (size_t)ROWS*DI;                  // 4*512*128 f16
  f16* wf_xp  = wf_in + (size_t)4*2*DI*DM;            // 4*40*256 f16
  f16* wf_out = wf_xp + (size_t)4*40*DI;              // 4*128*256 f16

  hipMemcpyAsync(h, x, (size_t)ROWS*DM*sizeof(float), hipMemcpyDeviceToDevice, stream);

  // one-time weight conversion fp32 -> fp16
  cvt_kernel<<<(4*2*DI*DM)/1024, 256, 0, stream>>>(in_w, wf_in, (4*2*DI*DM)/4);
  cvt_kernel<<<(4*40*DI)/1024, 256, 0, stream>>>(xp_w, wf_xp, (4*40*DI)/4);
  cvt_kernel<<<(4*DM*DI)/1024, 256, 0, stream>>>(out_w, wf_out, (4*DM*DI)/4);

  for (int layer = 0; layer < 4; ++layer) {
    const f16*  lw_in  = wf_in  + (size_t)layer*2*DI*DM;
    const float* lw_cw  = conv_w + (size_t)layer*DI*4;
    const float* lw_cb  = conv_b + (size_t)layer*DI;
    const f16*  lw_xp  = wf_xp  + (size_t)layer*40*DI;
    const float* lw_dtw = dt_w  + (size_t)layer*DI*8;
    const float* lw_dtb = dt_b  + (size_t)layer*DI;
    const float* lw_Al  = A_log + (size_t)layer*DI*DSN;
    const float* lw_D   = Dp    + (size_t)layer*DI;
    const f16*  lw_out = wf_out + (size_t)layer*DM*DI;
    const float* lw_nw  = norm_w + (size_t)layer*DM;

    rmsnorm_kernel<<<ROWS/4, 256, 0, stream>>>(h, lw_nw, xn);
    gemm_f16<true,false><<<dim3(ROWS/64, 512/64), 256, 0, stream>>>(xn, lw_in, nullptr, xz, ROWS, 512, DM);
    conv_silu_kernel<<<ROWS, 256, 0, stream>>>(xz, lw_cw, lw_cb, xs);
    gemm_f16<false,false><<<dim3(ROWS/64, 1), 256, 0, stream>>>(xs, lw_xp, nullptr, dbc, ROWS, 40, DI);
    scan_p1<<<NB*NCHUNK, 256, 0, stream>>>(xs, dbc, lw_Al, lw_dtw, lw_dtb, S, sumdl);
    scan_p2<<<NB*DI*DSN/256, 256, 0, stream>>>(S, sumdl, lw_Al);
    scan_p3<<<NB*NCHUNK, 256, 0, stream>>>(xs, dbc, lw_Al, lw_dtw, lw_dtb, lw_D, S, xz, y);
    gemm_f16<false,true><<<dim3(ROWS/64, DM/64), 256, 0, stream>>>(y, lw_out, h, h, ROWS, DM, DI);
  }
  final_kernel<<<1, 256, 0, stream>>>(h, norm_f, gamma, beta, head_w, head_b, (float*)d_out);
}

// Round 4
// 308.326 us; speedup vs baseline: 4.0201x; 1.2344x over previous
//
#include <hip/hip_runtime.h>
#include <cstddef>

#define LQ 1024
#define DM 128
#define DI 256
#define DSN 16
#define NB 8
#define ROWS (NB*LQ)
#define EPSF 1e-5f
#define CHUNK 32
#define NCHUNK (LQ/CHUNK)

typedef _Float16 f16;
typedef __attribute__((ext_vector_type(8))) _Float16 f16x8;
typedef __attribute__((ext_vector_type(4))) _Float16 f16x4;
typedef __attribute__((ext_vector_type(4))) float f32x4;

static __device__ __forceinline__ float sigmoid_f(float x) { return 1.f/(1.f+__expf(-x)); }
static __device__ __forceinline__ float softplus_f(float x) {
  return (x > 20.f) ? x : log1pf(__expf(x));
}

// ---------------- one-shot fp32 -> fp16 conversion of all three weight sets ----------------
__global__ __launch_bounds__(256) void cvt_all(
    const float* __restrict__ a, const float* __restrict__ bsrc, const float* __restrict__ csrc,
    f16* __restrict__ oa, f16* __restrict__ ob, f16* __restrict__ oc)
{
  int i = blockIdx.x*256 + threadIdx.x;
  const int na = (4*2*DI*DM)/4;   // 65536 float4 groups
  const int nb = (4*40*DI)/4;     // 10240
  const int nc = (4*DM*DI)/4;     // 32768
  const float* s; f16* o; int k;
  if (i < na)            { s = a;    o = oa; k = i; }
  else if (i < na+nb)    { s = bsrc; o = ob; k = i - na; }
  else if (i < na+nb+nc) { s = csrc; o = oc; k = i - na - nb; }
  else return;
  float4 v = ((const float4*)s)[k];
  f16x4 r; r.x=(f16)v.x; r.y=(f16)v.y; r.z=(f16)v.z; r.w=(f16)v.w;
  ((f16x4*)o)[k] = r;
}

// ---------------- K1: fused rmsnorm + in_proj GEMM (M=64,N=64,K=128) ----------------
__global__ __launch_bounds__(256) void norm_inproj(
    const float* __restrict__ hin, const float* __restrict__ nw,
    const f16* __restrict__ Wf, f16* __restrict__ xz)
{
  __shared__ __align__(16) f16 Alds[64][136];
  __shared__ __align__(16) f16 Blds[64][136];
  const int tid = threadIdx.x;
  const int row0 = blockIdx.x*64, col0 = blockIdx.y*64;
  // stage W tile
  #pragma unroll
  for (int cc = tid; cc < 1024; cc += 256) {
    int r = cc >> 4, off = (cc & 15) << 3;
    *(f16x8*)&Blds[r][off] = *(const f16x8*)(Wf + (size_t)(col0 + r)*DM + off);
  }
  // stage A tile with fused rmsnorm (4 lanes per row)
  {
    const int r = tid >> 2, seg = (tid & 3) * 32;
    const float* hr = hin + (size_t)(row0 + r)*DM + seg;
    float4 v[8];
    float ss = 0.f;
    #pragma unroll
    for (int j = 0; j < 8; ++j) {
      v[j] = *(const float4*)(hr + j*4);
      ss += v[j].x*v[j].x + v[j].y*v[j].y + v[j].z*v[j].z + v[j].w*v[j].w;
    }
    ss += __shfl_xor(ss, 1);
    ss += __shfl_xor(ss, 2);
    const float sc = rsqrtf(ss*(1.f/128.f) + EPSF);
    #pragma unroll
    for (int j = 0; j < 8; ++j) {
      float4 wv = *(const float4*)(nw + seg + j*4);
      f16x4 o;
      o.x = (f16)(v[j].x*sc*wv.x);
      o.y = (f16)(v[j].y*sc*wv.y);
      o.z = (f16)(v[j].z*sc*wv.z);
      o.w = (f16)(v[j].w*sc*wv.w);
      *(f16x4*)&Alds[r][seg + j*4] = o;
    }
  }
  __syncthreads();
  const int l = tid & 63, w = tid >> 6;
  const int wr = w >> 1, wc = w & 1;
  const int fr = l & 15, kg = l >> 4;
  f16x8 af[2][4], bf[2][4];
  #pragma unroll
  for (int m = 0; m < 2; ++m)
    #pragma unroll
    for (int s = 0; s < 4; ++s)
      af[m][s] = *(const f16x8*)&Alds[wr*32 + m*16 + fr][s*32 + kg*8];
  #pragma unroll
  for (int n = 0; n < 2; ++n)
    #pragma unroll
    for (int s = 0; s < 4; ++s)
      bf[n][s] = *(const f16x8*)&Blds[wc*32 + n*16 + fr][s*32 + kg*8];
  f32x4 acc[2][2];
  #pragma unroll
  for (int m = 0; m < 2; ++m)
    #pragma unroll
    for (int n = 0; n < 2; ++n)
      acc[m][n] = (f32x4){0.f,0.f,0.f,0.f};
  #pragma unroll
  for (int s = 0; s < 4; ++s)
    #pragma unroll
    for (int m = 0; m < 2; ++m)
      #pragma unroll
      for (int n = 0; n < 2; ++n)
        acc[m][n] = __builtin_amdgcn_mfma_f32_16x16x32_f16(af[m][s], bf[n][s], acc[m][n], 0, 0, 0);
  #pragma unroll
  for (int m = 0; m < 2; ++m)
    #pragma unroll
    for (int n = 0; n < 2; ++n) {
      const int col = col0 + wc*32 + n*16 + fr;
      #pragma unroll
      for (int j = 0; j < 4; ++j) {
        const int row = row0 + wr*32 + m*16 + kg*4 + j;
        xz[(size_t)row*(2*DI) + col] = (f16)acc[m][n][j];
      }
    }
}

// ---------------- K2: conv+silu + x_proj GEMM + scan phase 1 (block = batch x 32-chunk) ----------------
__global__ __launch_bounds__(256) void conv_xproj_p1(
    const f16* __restrict__ xz, const float* __restrict__ cw, const float* __restrict__ cb,
    const f16* __restrict__ xpw, const float* __restrict__ A_log,
    const float* __restrict__ dtw, const float* __restrict__ dtb,
    f16* __restrict__ xs_out, float* __restrict__ dbc_out,
    float* __restrict__ S, float* __restrict__ sumdl_out)
{
  __shared__ __align__(16) f16 sXz[35][256];   // halo x-part rows t0-3..t0+31
  __shared__ __align__(16) f16 sXs[32][264];
  __shared__ __align__(16) f16 sW[48][264];    // xp_w padded to 48 rows (40 valid, rest 0)
  __shared__ __align__(16) float sDbc[32][40];
  const int bc = blockIdx.x;
  const int b = bc >> 5, ck = bc & (NCHUNK-1);
  const int t0 = ck*CHUNK;
  const int tid = threadIdx.x;
  // stage halo xz (x half only)
  for (int e = tid; e < 35*32; e += 256) {
    int r = e >> 5, off = (e & 31) << 3;
    f16x8 v = (f16x8){0,0,0,0,0,0,0,0};
    if (ck > 0 || r >= 3)
      v = *(const f16x8*)(xz + (size_t)(b*LQ + t0 - 3 + r)*(2*DI) + off);
    *(f16x8*)&sXz[r][off] = v;
  }
  // stage xp_w (rows >= 40 zeroed)
  for (int e = tid; e < 48*32; e += 256) {
    int r = e >> 5, off = (e & 31) << 3;
    f16x8 v = (f16x8){0,0,0,0,0,0,0,0};
    if (r < 40) v = *(const f16x8*)(xpw + (size_t)r*DI + off);
    *(f16x8*)&sW[r][off] = v;
  }
  __syncthreads();
  // conv + silu (thread = channel)
  {
    const int d = tid;
    const float4 cwv = *(const float4*)(cw + d*4);
    const float bias = cb[d];
    #pragma unroll 4
    for (int t = 0; t < CHUNK; ++t) {
      float acc = bias + (float)sXz[t][d]*cwv.x + (float)sXz[t+1][d]*cwv.y
                       + (float)sXz[t+2][d]*cwv.z + (float)sXz[t+3][d]*cwv.w;
      float sv = acc * sigmoid_f(acc);
      f16 s16 = (f16)sv;
      sXs[t][d] = s16;
      xs_out[(size_t)(b*LQ + t0 + t)*DI + d] = s16;
    }
  }
  __syncthreads();
  // x_proj GEMM: xs(32x256) @ xpw(40x256)^T, waves 0..2 take one 16-col N-frag each
  const int l = tid & 63, w = tid >> 6;
  const int fr = l & 15, kg = l >> 4;
  if (w < 3) {
    f32x4 acc[2];
    acc[0] = (f32x4){0.f,0.f,0.f,0.f};
    acc[1] = (f32x4){0.f,0.f,0.f,0.f};
    #pragma unroll
    for (int s = 0; s < 8; ++s) {
      f16x8 bfv = *(const f16x8*)&sW[w*16 + fr][s*32 + kg*8];
      #pragma unroll
      for (int m = 0; m < 2; ++m) {
        f16x8 afv = *(const f16x8*)&sXs[m*16 + fr][s*32 + kg*8];
        acc[m] = __builtin_amdgcn_mfma_f32_16x16x32_f16(afv, bfv, acc[m], 0, 0, 0);
      }
    }
    const int col = w*16 + fr;
    if (col < 40) {
      #pragma unroll
      for (int m = 0; m < 2; ++m)
        #pragma unroll
        for (int j = 0; j < 4; ++j) {
          int row = m*16 + kg*4 + j;
          sDbc[row][col] = acc[m][j];
          dbc_out[(size_t)(b*LQ + t0 + row)*40 + col] = acc[m][j];
        }
    }
  }
  __syncthreads();
  // scan phase 1 (thread = channel): dt fused, h local, emit S + sum(delta)
  {
    const int d = tid;
    float A[16];
    #pragma unroll
    for (int n = 0; n < 16; ++n) A[n] = -__expf(A_log[d*16+n]);
    const float4 dw0 = *(const float4*)(dtw + d*8);
    const float4 dw1 = *(const float4*)(dtw + d*8 + 4);
    const float bt = dtb[d];
    float h[16] = {};
    float sdl = 0.f;
    for (int t = 0; t < CHUNK; ++t) {
      float xa = bt + sDbc[t][0]*dw0.x + sDbc[t][1]*dw0.y + sDbc[t][2]*dw0.z + sDbc[t][3]*dw0.w
                    + sDbc[t][4]*dw1.x + sDbc[t][5]*dw1.y + sDbc[t][6]*dw1.z + sDbc[t][7]*dw1.w;
      float dl = softplus_f(xa);
      float uu = (float)sXs[t][d];
      float du = dl*uu;
      sdl += dl;
      #pragma unroll
      for (int n = 0; n < 16; ++n)
        h[n] = __expf(dl*A[n])*h[n] + du*sDbc[t][8+n];
    }
    float* Sp = S + ((size_t)bc*DI + d)*16;
    #pragma unroll
    for (int n = 0; n < 16; n += 4)
      *(float4*)(Sp+n) = make_float4(h[n],h[n+1],h[n+2],h[n+3]);
    sumdl_out[(size_t)bc*DI + d] = sdl;
  }
}

// ---------------- K3: exclusive scan over chunks (in-place S -> Hinit) ----------------
__global__ __launch_bounds__(256) void scan_p2(
    float* __restrict__ S, const float* __restrict__ sumdl,
    const float* __restrict__ A_log)
{
  int g = blockIdx.x*256 + threadIdx.x;   // b*4096 + d*16 + n
  int b = g >> 12;
  int dn = g & 4095;
  float A = -__expf(A_log[dn]);
  int d = dn >> 4;
  float H = 0.f;
  for (int c = 0; c < NCHUNK; ++c) {
    size_t cidx = (size_t)(b*NCHUNK + c)*DI + d;
    size_t idx = cidx*16 + (dn & 15);
    float Sv = S[idx];
    float P = __expf(A * sumdl[cidx]);
    S[idx] = H;
    H = P*H + Sv;
  }
}

// ---------------- K4: scan phase 3 + gate + out_proj GEMM + residual ----------------
__global__ __launch_bounds__(256) void p3_outproj(
    const f16* __restrict__ xs, const float* __restrict__ dbc,
    const float* __restrict__ A_log, const float* __restrict__ dtw,
    const float* __restrict__ dtb, const float* __restrict__ Dp,
    const float* __restrict__ Hinit, const f16* __restrict__ xz,
    const f16* __restrict__ Wo, const float* __restrict__ addsrc,
    float* __restrict__ hout)
{
  __shared__ __align__(16) f16 sY[32][264];
  __shared__ float sB[CHUNK][16];
  __shared__ float sC[CHUNK][16];
  __shared__ float sDL[CHUNK][8];
  const int bc = blockIdx.x;
  const int b = bc >> 5, ck = bc & (NCHUNK-1);
  const int t0 = ck*CHUNK;
  const int tid = threadIdx.x;
  for (int e = tid; e < CHUNK*16; e += 256) {
    int t = e >> 4, n = e & 15;
    size_t r = (size_t)(b*LQ + t0 + t)*40;
    sB[t][n] = dbc[r + 8 + n];
    sC[t][n] = dbc[r + 24 + n];
  }
  for (int e = tid; e < CHUNK*8; e += 256) {
    int t = e >> 3, j = e & 7;
    sDL[t][j] = dbc[(size_t)(b*LQ + t0 + t)*40 + j];
  }
  const int d = tid;
  float A[16];
  #pragma unroll
  for (int n = 0; n < 16; ++n) A[n] = -__expf(A_log[d*16+n]);
  const float4 dw0 = *(const float4*)(dtw + d*8);
  const float4 dw1 = *(const float4*)(dtw + d*8 + 4);
  const float bt = dtb[d];
  const float Dv = Dp[d];
  float h[16];
  const float* Hp = Hinit + ((size_t)bc*DI + d)*16;
  #pragma unroll
  for (int n = 0; n < 16; n += 4) {
    float4 v = *(const float4*)(Hp+n);
    h[n]=v.x; h[n+1]=v.y; h[n+2]=v.z; h[n+3]=v.w;
  }
  __syncthreads();
  const size_t ubase = (size_t)(b*LQ + t0)*DI + d;
  const size_t rbase = (size_t)(b*LQ + t0)*(2*DI) + DI + d;
  for (int t = 0; t < CHUNK; ++t) {
    float xa = bt + sDL[t][0]*dw0.x + sDL[t][1]*dw0.y + sDL[t][2]*dw0.z + sDL[t][3]*dw0.w
                  + sDL[t][4]*dw1.x + sDL[t][5]*dw1.y + sDL[t][6]*dw1.z + sDL[t][7]*dw1.w;
    float dl = softplus_f(xa);
    float uu = (float)xs[ubase + (size_t)t*DI];
    float du = dl*uu;
    float acc = uu*Dv;
    #pragma unroll
    for (int n = 0; n < 16; ++n) {
      h[n] = __expf(dl*A[n])*h[n] + du*sB[t][n];
      acc += h[n]*sC[t][n];
    }
    float res = (float)xz[rbase + (size_t)t*(2*DI)];
    sY[t][d] = (f16)(acc * (res * sigmoid_f(res)));
  }
  __syncthreads();
  // out_proj GEMM: y(32x256) @ Wo(128x256)^T + residual; W read from global (L2-hot)
  const int l = tid & 63, w = tid >> 6;
  const int fr = l & 15, kg = l >> 4;
  f16x8 bf[2][8];
  #pragma unroll
  for (int n = 0; n < 2; ++n)
    #pragma unroll
    for (int s = 0; s < 8; ++s)
      bf[n][s] = *(const f16x8*)(Wo + (size_t)(w*32 + n*16 + fr)*DI + s*32 + kg*8);
  f32x4 acc[2][2];
  #pragma unroll
  for (int m = 0; m < 2; ++m)
    #pragma unroll
    for (int n = 0; n < 2; ++n)
      acc[m][n] = (f32x4){0.f,0.f,0.f,0.f};
  #pragma unroll
  for (int s = 0; s < 8; ++s)
    #pragma unroll
    for (int m = 0; m < 2; ++m) {
      f16x8 afv = *(const f16x8*)&sY[m*16 + fr][s*32 + kg*8];
      #pragma unroll
      for (int n = 0; n < 2; ++n)
        acc[m][n] = __builtin_amdgcn_mfma_f32_16x16x32_f16(afv, bf[n][s], acc[m][n], 0, 0, 0);
    }
  #pragma unroll
  for (int m = 0; m < 2; ++m)
    #pragma unroll
    for (int n = 0; n < 2; ++n) {
      const int col = w*32 + n*16 + fr;
      #pragma unroll
      for (int j = 0; j < 4; ++j) {
        const int row = m*16 + kg*4 + j;
        const size_t gi = (size_t)(b*LQ + t0 + row)*DM + col;
        hout[gi] = acc[m][n][j] + addsrc[gi];
      }
    }
}

// ---------------- final: last-token rmsnorm + batchnorm + relu + head ----------------
__global__ __launch_bounds__(256) void final_kernel(const float* __restrict__ h,
    const float* __restrict__ nfw, const float* __restrict__ gamma, const float* __restrict__ beta,
    const float* __restrict__ hw, const float* __restrict__ hb, float* __restrict__ out) {
  __shared__ float sf[8][128];
  __shared__ float sscale[8];
  int tid = threadIdx.x;
  for (int e = tid; e < 1024; e += 256) {
    int b = e >> 7, dd = e & 127;
    sf[b][dd] = h[((size_t)b*LQ + (LQ-1))*DM + dd];
  }
  __syncthreads();
  if (tid < 8) {
    float ss = 0.f;
    for (int dd = 0; dd < 128; ++dd) { float v = sf[tid][dd]; ss += v*v; }
    sscale[tid] = rsqrtf(ss/128.f + EPSF);
  }
  __syncthreads();
  for (int e = tid; e < 1024; e += 256) {
    int b = e >> 7, dd = e & 127;
    sf[b][dd] = sf[b][dd]*sscale[b]*nfw[dd];
  }
  __syncthreads();
  if (tid < 128) {
    float mu = 0.f;
    for (int b = 0; b < 8; ++b) mu += sf[b][tid];
    mu *= 0.125f;
    float var = 0.f;
    for (int b = 0; b < 8; ++b) { float dv = sf[b][tid]-mu; var += dv*dv; }
    var *= 0.125f;
    float rs = rsqrtf(var + EPSF);
    for (int b = 0; b < 8; ++b) {
      float v = (sf[b][tid]-mu)*rs*gamma[tid] + beta[tid];
      sf[b][tid] = v > 0.f ? v : 0.f;
    }
  }
  __syncthreads();
  if (tid < 16) {
    int b = tid >> 1, s = tid & 1;
    float acc = hb[s];
    for (int dd = 0; dd < 128; ++dd) acc += sf[b][dd]*hw[s*128+dd];
    out[b*2+s] = acc;
  }
}

extern "C" void kernel_launch(void* const* d_in, const int* in_sizes, int n_in,
                              void* d_out, int out_size, void* d_ws, size_t ws_size,
                              hipStream_t stream) {
  const float* x      = (const float*)d_in[0];
  const float* in_w   = (const float*)d_in[1];
  const float* conv_w = (const float*)d_in[2];
  const float* conv_b = (const float*)d_in[3];
  const float* xp_w   = (const float*)d_in[4];
  const float* dt_w   = (const float*)d_in[5];
  const float* dt_b   = (const float*)d_in[6];
  const float* A_log  = (const float*)d_in[7];
  const float* Dp     = (const float*)d_in[8];
  const float* out_w  = (const float*)d_in[9];
  const float* norm_w = (const float*)d_in[10];
  const float* norm_f = (const float*)d_in[11];
  const float* gamma  = (const float*)d_in[12];
  const float* beta   = (const float*)d_in[13];
  const float* head_w = (const float*)d_in[14];
  const float* head_b = (const float*)d_in[15];

  float* ws = (float*)d_ws;
  float* h     = ws;                             // ROWS*DM fp32
  float* dbc   = h + (size_t)ROWS*DM;            // ROWS*40 fp32
  float* S     = dbc + (size_t)ROWS*40;          // NB*NCHUNK*DI*16 fp32
  float* sumdl = S + (size_t)NB*NCHUNK*DI*16;    // NB*NCHUNK*DI fp32
  f16* xz     = (f16*)(sumdl + (size_t)NB*NCHUNK*DI); // ROWS*512 f16
  f16* xs     = xz + (size_t)ROWS*2*DI;               // ROWS*256 f16
  f16* wf_in  = xs + (size_t)ROWS*DI;                 // 4*512*128 f16
  f16* wf_xp  = wf_in + (size_t)4*2*DI*DM;            // 4*40*256 f16
  f16* wf_out = wf_xp + (size_t)4*40*DI;              // 4*128*256 f16

  cvt_all<<<424, 256, 0, stream>>>(in_w, xp_w, out_w, wf_in, wf_xp, wf_out);

  for (int layer = 0; layer < 4; ++layer) {
    const float* src = layer ? h : x;   // rmsnorm input and residual source
    norm_inproj<<<dim3(ROWS/64, 8), 256, 0, stream>>>(
        src, norm_w + (size_t)layer*DM, wf_in + (size_t)layer*2*DI*DM, xz);
    conv_xproj_p1<<<NB*NCHUNK, 256, 0, stream>>>(
        xz, conv_w + (size_t)layer*DI*4, conv_b + (size_t)layer*DI,
        wf_xp + (size_t)layer*40*DI, A_log + (size_t)layer*DI*DSN,
        dt_w + (size_t)layer*DI*8, dt_b + (size_t)layer*DI,
        xs, dbc, S, sumdl);
    scan_p2<<<NB*DI*DSN/256, 256, 0, stream>>>(S, sumdl, A_log + (size_t)layer*DI*DSN);
    p3_outproj<<<NB*NCHUNK, 256, 0, stream>>>(
        xs, dbc, A_log + (size_t)layer*DI*DSN, dt_w + (size_t)layer*DI*8,
        dt_b + (size_t)layer*DI, Dp + (size_t)layer*DI, S, xz,
        wf_out + (size_t)layer*DM*DI, src, h);
  }
  final_kernel<<<1, 256, 0, stream>>>(h, norm_f, gamma, beta, head_w, head_b, (float*)d_out);
}